// Round 8
// baseline (232.842 us; speedup 1.0000x reference)
//
#include <hip/hip_runtime.h>
#include <hip/hip_bf16.h>

#define NC 10
#define DD 64
#define BB 32
#define SS 16384
#define CH 256                               // rows per seg block
#define NCH (SS / CH)                        // 64 chunks per b
#define NBLK (BB * NCH)                      // 2048
#define TSTR 65                              // LDS tile row stride (pad)
#define TSZ (NC * TSTR)                      // 650
#define OUT_MAIN (2 * BB * NC * DD)          // 40960
// ws: seg_part [2048][640] f32 | cnt_part [2048][10] i32 = 5.3 MB
#define SEG_WORDS (NBLK * NC * DD)
#define WS_WORDS (SEG_WORDS + NBLK * NC)

// ------------------------------------------------- kernel 1: segment sums ---
// 2048 blocks x 256 thr = exactly 8 blocks/CU -> 32 waves/CU (full TLP).
// Lane = dim; row label is wave-uniform (v_readlane -> SGPR); 10 register
// accumulators, branchless scalar-mask fmac. ZERO LDS/global atomics for
// sums; per-block partials stored plain (no zero pass needed).
__global__ __launch_bounds__(256) void seg_kernel(
    const float* __restrict__ x, const int* __restrict__ labels,
    float* __restrict__ seg_part, int* __restrict__ cnt_part)
{
    __shared__ float tiles[4][TSZ];            // 10,400 B
    __shared__ int scnt[NC];

    const int tid = threadIdx.x;
    const int blk = blockIdx.x;
    const int b = blk >> 6, chunk = blk & 63;
    const long row0 = (long)b * SS + chunk * CH;
    const int w = tid >> 6, lane = tid & 63;

    if (tid < NC) scnt[tid] = 0;

    // wave w owns rows [w*64, w*64+64); lane L holds label of row w*64+L
    const int lv = labels[row0 + w * 64 + lane];
    const float* xr = x + (row0 + w * 64) * DD + lane;

    float acc[NC];
    #pragma unroll
    for (int c = 0; c < NC; ++c) acc[c] = 0.f;

    for (int r1 = 0; r1 < 64; r1 += 8) {
        float v[8];
        #pragma unroll
        for (int u = 0; u < 8; ++u)            // 8 x 256B coalesced in flight
            v[u] = xr[(r1 + u) * DD];
        #pragma unroll
        for (int u = 0; u < 8; ++u) {
            const int l = __builtin_amdgcn_readlane(lv, r1 + u);  // SGPR
            #pragma unroll
            for (int c = 0; c < NC; ++c)       // s_cmp+s_cselect+v_fmac
                acc[c] = fmaf(v[u], (l == c) ? 1.f : 0.f, acc[c]);
        }
    }

    __syncthreads();                           // scnt zero visible

    #pragma unroll
    for (int c = 0; c < NC; ++c) {             // counts via ballot
        int n = (int)__popcll(__ballot(lv == c));
        if (lane == 0) atomicAdd(&scnt[c], n); // 40 LDS ops/block
    }
    #pragma unroll
    for (int c = 0; c < NC; ++c)               // regs -> wave tile (plain)
        tiles[w][c * TSTR + lane] = acc[c];
    __syncthreads();

    float* sp = seg_part + (long)blk * (NC * DD);
    for (int i = tid; i < NC * DD; i += 256) { // merge 4 waves, plain store
        const int c = i >> 6, d = i & 63;
        sp[i] = tiles[0][c * TSTR + d] + tiles[1][c * TSTR + d]
              + tiles[2][c * TSTR + d] + tiles[3][c * TSTR + d];
    }
    if (tid < NC) cnt_part[blk * NC + tid] = scnt[tid];
}

// --------------------------------------------------- kernel 2: MLP heads ----
// 64 blocks (b x head) x 1024 thr. Step 1: reduce 64 chunk-partials (threads
// 0..639, coalesced, 8-deep ILP; wave 10 reduces counts). Step 2: 3-layer
// MLP, one float4 weight stage per thread/layer, waves 0..9 = cluster rows.
__global__ __launch_bounds__(1024) void mlp_kernel(
    const float* __restrict__ seg_part, const int* __restrict__ cnt_part,
    const float* wm1, const float* bm1, const float* wm2, const float* bm2,
    const float* wm3, const float* bm3,
    const float* wv1, const float* bv1, const float* wv2, const float* bv2,
    const float* wv3, const float* bv3,
    float* __restrict__ out)
{
    const int blk = blockIdx.x;                // b*2 + head
    const int b = blk >> 1, head = blk & 1;
    const int tid = threadIdx.x;
    const int w = tid >> 6, lane = tid & 63;

    __shared__ float w_lds[DD * TSTR];         // 16,640 B
    __shared__ float hs[NC][DD];
    __shared__ int scnt[NC];

    if (tid >= 640 && tid < 640 + NC) {        // wave 10: count reduce
        const int c = tid - 640;
        int s = 0;
        for (int ch0 = 0; ch0 < NCH; ch0 += 8) {
            int t[8];
            #pragma unroll
            for (int u = 0; u < 8; ++u)
                t[u] = cnt_part[(b * NCH + ch0 + u) * NC + c];
            #pragma unroll
            for (int u = 0; u < 8; ++u) s += t[u];
        }
        scnt[c] = s;
    }

    float sv = 0.f;
    if (tid < NC * DD) {                       // waves 0..9: slot reduce
        const float* sp = seg_part + (long)(b * NCH) * (NC * DD) + tid;
        for (int ch0 = 0; ch0 < NCH; ch0 += 8) {
            float t[8];
            #pragma unroll
            for (int u = 0; u < 8; ++u)        // 8 x 2.5KB-strided, coalesced
                t[u] = sp[(long)(ch0 + u) * (NC * DD)];
            #pragma unroll
            for (int u = 0; u < 8; ++u) sv += t[u];
        }
    }
    __syncthreads();                           // scnt ready
    if (tid < NC * DD)
        hs[w][lane] = sv / (float)scnt[w];     // row w: written/read by wave w

    const float* Wl[3] = {head ? wv1 : wm1, head ? wv2 : wm2, head ? wv3 : wm3};
    const float* Bl[3] = {head ? bv1 : bm1, head ? bv2 : bm2, head ? bv3 : bm3};

    float val = 0.f;
    const int j = tid >> 4, d0 = (tid & 15) * 4;   // stage target

    #pragma unroll
    for (int layer = 0; layer < 3; ++layer) {
        const float4 wv = ((const float4*)Wl[layer])[tid];  // 1 insn / thread
        const float bias = (w < NC) ? Bl[layer][lane] : 0.f;
        __syncthreads();                       // prev-layer dots done
        w_lds[j * TSTR + d0 + 0] = wv.x;
        w_lds[j * TSTR + d0 + 1] = wv.y;
        w_lds[j * TSTR + d0 + 2] = wv.z;
        w_lds[j * TSTR + d0 + 3] = wv.w;
        __syncthreads();                       // W staged
        if (w < NC) {
            float z = bias;
            #pragma unroll
            for (int d = 0; d < DD; ++d)       // 2-way banks (free)
                z += hs[w][d] * w_lds[lane * TSTR + d];
            val = (layer < 2) ? fmaxf(z, 0.f)
                              : (2.f / (1.f + __expf(-z)) - 1.f);
            hs[w][lane] = val;                 // wave-internal, in-order
        }
    }
    if (w < NC)
        out[head * (BB * NC * DD) + (b * NC + w) * DD + lane] = val;
}

// ------------------- kernel 3: init vectors from d_out (2 blocks, no atomics)
__global__ __launch_bounds__(256) void init_kernel(
    const float* __restrict__ out_ro, const int* __restrict__ Kptr,
    float* __restrict__ out)
{
    const int head = blockIdx.x, tid = threadIdx.x;
    const int d = tid & 63, grp = tid >> 6;    // 4 row-groups
    __shared__ float part[4][DD];

    const float* src = out_ro + head * (BB * NC * DD);
    float s = 0.f;
    for (int r0 = 0; r0 < 80; r0 += 8) {       // 320 rows / 4 groups, ILP 8
        float t[8];
        #pragma unroll
        for (int u = 0; u < 8; ++u)            // coalesced 256B per row
            t[u] = src[(grp + (r0 + u) * 4) * DD + d];
        #pragma unroll
        for (int u = 0; u < 8; ++u) s += t[u];
    }
    part[grp][d] = s;
    __syncthreads();
    if (tid < DD)
        out[OUT_MAIN + head * DD + tid] =
            (part[0][tid] + part[1][tid] + part[2][tid] + part[3][tid])
            / (float)(BB * Kptr[0]);
}

// ------------------------------------- fallback: fused, zero-ws, 32 blocks --
__global__ __launch_bounds__(1024) void fused_fallback_kernel(
    const float* __restrict__ x, const int* __restrict__ labels,
    const float* wm1, const float* bm1, const float* wm2, const float* bm2,
    const float* wm3, const float* bm3,
    const float* wv1, const float* bv1, const float* wv2, const float* bv2,
    const float* wv3, const float* bv3,
    float* __restrict__ out)
{
    __shared__ float ssum[NC * DD];
    __shared__ int scnt[NC];
    __shared__ float hs[NC][DD];
    __shared__ float w_lds[DD * (DD + 1)];

    const int tid = threadIdx.x;
    const int b = blockIdx.x;
    const int wave = tid >> 6, lane = tid & 63;

    for (int i = tid; i < NC * DD; i += 1024) ssum[i] = 0.f;
    if (tid < NC) scnt[tid] = 0;
    __syncthreads();

    const int* lab = labels + b * SS;
    {
        int c_acc[NC];
        #pragma unroll
        for (int c = 0; c < NC; ++c) c_acc[c] = 0;
        for (int i = 0; i < 16; ++i) {
            int l = lab[wave * 1024 + i * 64 + lane];
            #pragma unroll
            for (int c = 0; c < NC; ++c)
                c_acc[c] += (int)__popcll(__ballot(l == c));
        }
        if (lane == 0) {
            #pragma unroll
            for (int c = 0; c < NC; ++c) atomicAdd(&scnt[c], c_acc[c]);
        }
    }

    const float* xb = x + ((long)b * SS + wave * 1024) * DD + lane;
    const int* labw = lab + wave * 1024;
    for (int r = 0; r < 1024; r += 8) {
        float v[8]; int l[8];
        #pragma unroll
        for (int u = 0; u < 8; ++u) { v[u] = xb[(r + u) * DD]; l[u] = labw[r + u]; }
        #pragma unroll
        for (int u = 0; u < 8; ++u) atomicAdd(&ssum[l[u] * DD + lane], v[u]);
    }
    __syncthreads();

    const int c = tid >> 6;
    const bool act = (tid < NC * DD);
    float slot = 0.f;
    if (act) slot = ssum[c * DD + lane] / (float)scnt[c];

    const float* Ws[2][3] = {{wm1, wm2, wm3}, {wv1, wv2, wv3}};
    const float* Bs[2][3] = {{bm1, bm2, bm3}, {bv1, bv2, bv3}};

    #pragma unroll
    for (int head = 0; head < 2; ++head) {
        if (act) hs[c][lane] = slot;
        float val = 0.f;
        #pragma unroll
        for (int layer = 0; layer < 3; ++layer) {
            const float* W = Ws[head][layer];
            for (int i = tid; i < DD * DD; i += 1024)
                w_lds[(i >> 6) * (DD + 1) + (i & 63)] = W[i];
            __syncthreads();
            if (act) {
                float z = Bs[head][layer][lane];
                #pragma unroll
                for (int d = 0; d < DD; ++d)
                    z += hs[c][d] * w_lds[lane * (DD + 1) + d];
                val = (layer < 2) ? fmaxf(z, 0.f)
                                  : (2.f / (1.f + __expf(-z)) - 1.f);
            }
            __syncthreads();
            if (act) hs[c][lane] = val;
        }
        if (act) out[head * (BB * NC * DD) + (b * NC + c) * DD + lane] = val;
        __syncthreads();
    }
}

extern "C" void kernel_launch(void* const* d_in, const int* in_sizes, int n_in,
                              void* d_out, int out_size, void* d_ws, size_t ws_size,
                              hipStream_t stream)
{
    const float* x      = (const float*)d_in[0];
    const int*   labels = (const int*)d_in[1];
    const int*   K      = (const int*)d_in[2];
    const float* wm1 = (const float*)d_in[3];
    const float* bm1 = (const float*)d_in[4];
    const float* wm2 = (const float*)d_in[5];
    const float* bm2 = (const float*)d_in[6];
    const float* wm3 = (const float*)d_in[7];
    const float* bm3 = (const float*)d_in[8];
    const float* wv1 = (const float*)d_in[9];
    const float* bv1 = (const float*)d_in[10];
    const float* wv2 = (const float*)d_in[11];
    const float* bv2 = (const float*)d_in[12];
    const float* wv3 = (const float*)d_in[13];
    const float* bv3 = (const float*)d_in[14];
    float* out = (float*)d_out;

    if (ws_size >= (size_t)WS_WORDS * 4) {
        float* seg_part = (float*)d_ws;
        int*   cnt_part = (int*)((char*)d_ws + (size_t)SEG_WORDS * 4);
        seg_kernel<<<NBLK, 256, 0, stream>>>(x, labels, seg_part, cnt_part);
        mlp_kernel<<<2 * BB, 1024, 0, stream>>>(
            seg_part, cnt_part,
            wm1, bm1, wm2, bm2, wm3, bm3,
            wv1, bv1, wv2, bv2, wv3, bv3, out);
        init_kernel<<<2, 256, 0, stream>>>((const float*)d_out, K, out);
    } else {
        fused_fallback_kernel<<<BB, 1024, 0, stream>>>(
            x, labels,
            wm1, bm1, wm2, bm2, wm3, bm3,
            wv1, bv1, wv2, bv2, wv3, bv3, out);
        init_kernel<<<2, 256, 0, stream>>>((const float*)d_out, K, out);
    }
}

// Round 9
// 231.032 us; speedup vs baseline: 1.0078x; 1.0078x over previous
//
#include <hip/hip_runtime.h>
#include <hip/hip_bf16.h>

#define NC 10
#define DD 64
#define BB 32
#define SS 16384
#define CH 256                               // rows per seg block
#define NCH (SS / CH)                        // 64 chunks per b
#define NBLK (BB * NCH)                      // 2048
#define TSTR 65                              // LDS tile row stride (pad)
#define TSZ (NC * TSTR)                      // 650
#define OUT_MAIN (2 * BB * NC * DD)          // 40960
// ws: seg_part [2048][640] f32 | cnt_part [2048][10] i32 = 5.3 MB
#define SEG_WORDS (NBLK * NC * DD)
#define WS_WORDS (SEG_WORDS + NBLK * NC)

// ------------------------------------------------- kernel 1: segment sums ---
// 2048 blocks x 256 thr = 8 blocks/CU -> 32 waves/CU. Lane = dim; row label
// is wave-uniform (v_readlane -> SGPR); 10 register accumulators, branchless
// scalar-mask fmac (rounds 3/4/6 proved ds_add_f32 at ~3.2 cy/lane-RMW was
// the 174 us wall; registers removed it). Partials stored plain. Block 0
// also zeroes the init-accumulator region of out (ordered by kernel bound).
__global__ __launch_bounds__(256) void seg_kernel(
    const float* __restrict__ x, const int* __restrict__ labels,
    float* __restrict__ seg_part, int* __restrict__ cnt_part,
    float* __restrict__ out)
{
    __shared__ float tiles[4][TSZ];            // 10,400 B
    __shared__ int scnt[NC];

    const int tid = threadIdx.x;
    const int blk = blockIdx.x;
    const int b = blk >> 6, chunk = blk & 63;
    const long row0 = (long)b * SS + chunk * CH;
    const int w = tid >> 6, lane = tid & 63;

    if (blk == 0 && tid < 2 * DD) out[OUT_MAIN + tid] = 0.f;
    if (tid < NC) scnt[tid] = 0;

    // wave w owns rows [w*64, w*64+64); lane L holds label of row w*64+L
    const int lv = labels[row0 + w * 64 + lane];
    const float* xr = x + (row0 + w * 64) * DD + lane;

    float acc[NC];
    #pragma unroll
    for (int c = 0; c < NC; ++c) acc[c] = 0.f;

    for (int r1 = 0; r1 < 64; r1 += 8) {
        float v[8];
        #pragma unroll
        for (int u = 0; u < 8; ++u)            // 8 x 256B coalesced in flight
            v[u] = xr[(r1 + u) * DD];
        #pragma unroll
        for (int u = 0; u < 8; ++u) {
            const int l = __builtin_amdgcn_readlane(lv, r1 + u);  // SGPR
            #pragma unroll
            for (int c = 0; c < NC; ++c)       // s_cmp+s_cselect+v_fmac
                acc[c] = fmaf(v[u], (l == c) ? 1.f : 0.f, acc[c]);
        }
    }

    __syncthreads();                           // scnt zero visible

    #pragma unroll
    for (int c = 0; c < NC; ++c) {             // counts via ballot
        int n = (int)__popcll(__ballot(lv == c));
        if (lane == 0) atomicAdd(&scnt[c], n); // 40 LDS ops/block
    }
    #pragma unroll
    for (int c = 0; c < NC; ++c)               // regs -> wave tile (plain)
        tiles[w][c * TSTR + lane] = acc[c];
    __syncthreads();

    float* sp = seg_part + (long)blk * (NC * DD);
    for (int i = tid; i < NC * DD; i += 256) { // merge 4 waves, plain store
        const int c = i >> 6, d = i & 63;
        sp[i] = tiles[0][c * TSTR + d] + tiles[1][c * TSTR + d]
              + tiles[2][c * TSTR + d] + tiles[3][c * TSTR + d];
    }
    if (tid < NC) cnt_part[blk * NC + tid] = scnt[tid];
}

// ------------------------------------ kernel 2: MLP heads + init reduction --
// 64 blocks (b x head) x 1024 thr. Step 1: reduce 64 chunk-partials (threads
// 0..639 coalesced ILP-8; wave 10 reduces counts). Step 2: 3-layer MLP, one
// float4 weight stage per thread/layer, waves 0..9 = cluster rows. Step 3:
// per-block LDS reduce of the 10 rows -> 64 global f32 atomics into the
// init-accumulator region (pre-scaled by 1/(B*K)).
__global__ __launch_bounds__(1024) void mlp_kernel(
    const float* __restrict__ seg_part, const int* __restrict__ cnt_part,
    const float* wm1, const float* bm1, const float* wm2, const float* bm2,
    const float* wm3, const float* bm3,
    const float* wv1, const float* bv1, const float* wv2, const float* bv2,
    const float* wv3, const float* bv3,
    const int* __restrict__ Kptr, float* __restrict__ out)
{
    const int blk = blockIdx.x;                // b*2 + head
    const int b = blk >> 1, head = blk & 1;
    const int tid = threadIdx.x;
    const int w = tid >> 6, lane = tid & 63;

    __shared__ float w_lds[DD * TSTR];         // 16,640 B
    __shared__ float hs[NC][DD];
    __shared__ int scnt[NC];

    if (tid >= 640 && tid < 640 + NC) {        // wave 10: count reduce
        const int c = tid - 640;
        int s = 0;
        for (int ch0 = 0; ch0 < NCH; ch0 += 8) {
            int t[8];
            #pragma unroll
            for (int u = 0; u < 8; ++u)
                t[u] = cnt_part[(b * NCH + ch0 + u) * NC + c];
            #pragma unroll
            for (int u = 0; u < 8; ++u) s += t[u];
        }
        scnt[c] = s;
    }

    float sv = 0.f;
    if (tid < NC * DD) {                       // waves 0..9: slot reduce
        const float* sp = seg_part + (long)(b * NCH) * (NC * DD) + tid;
        for (int ch0 = 0; ch0 < NCH; ch0 += 8) {
            float t[8];
            #pragma unroll
            for (int u = 0; u < 8; ++u)        // coalesced, 8 in flight
                t[u] = sp[(long)(ch0 + u) * (NC * DD)];
            #pragma unroll
            for (int u = 0; u < 8; ++u) sv += t[u];
        }
    }
    __syncthreads();                           // scnt ready
    if (tid < NC * DD)
        hs[w][lane] = sv / (float)scnt[w];     // row w: written/read by wave w

    const float* Wl[3] = {head ? wv1 : wm1, head ? wv2 : wm2, head ? wv3 : wm3};
    const float* Bl[3] = {head ? bv1 : bm1, head ? bv2 : bm2, head ? bv3 : bm3};

    float val = 0.f;
    const int j = tid >> 4, d0 = (tid & 15) * 4;   // stage target

    #pragma unroll
    for (int layer = 0; layer < 3; ++layer) {
        const float4 wv = ((const float4*)Wl[layer])[tid];  // 1 insn / thread
        const float bias = (w < NC) ? Bl[layer][lane] : 0.f;
        __syncthreads();                       // prev-layer dots done
        w_lds[j * TSTR + d0 + 0] = wv.x;
        w_lds[j * TSTR + d0 + 1] = wv.y;
        w_lds[j * TSTR + d0 + 2] = wv.z;
        w_lds[j * TSTR + d0 + 3] = wv.w;
        __syncthreads();                       // W staged
        if (w < NC) {
            float z = bias;
            #pragma unroll
            for (int d = 0; d < DD; ++d)       // 2-way banks (free)
                z += hs[w][d] * w_lds[lane * TSTR + d];
            val = (layer < 2) ? fmaxf(z, 0.f)
                              : (2.f / (1.f + __expf(-z)) - 1.f);
            hs[w][lane] = val;                 // last layer leaves val in hs
        }
    }
    if (w < NC)
        out[head * (BB * NC * DD) + (b * NC + w) * DD + lane] = val;
    __syncthreads();                           // hs final for all 10 rows
    if (tid < DD) {
        float s = 0.f;
        #pragma unroll
        for (int c = 0; c < NC; ++c) s += hs[c][tid];
        unsafeAtomicAdd(&out[OUT_MAIN + head * DD + tid],
                        s / (float)(BB * Kptr[0]));
    }
}

// ------------------------------------- fallback: fused, zero-ws, 32 blocks --
__global__ __launch_bounds__(1024) void fused_fallback_kernel(
    const float* __restrict__ x, const int* __restrict__ labels,
    const float* wm1, const float* bm1, const float* wm2, const float* bm2,
    const float* wm3, const float* bm3,
    const float* wv1, const float* bv1, const float* wv2, const float* bv2,
    const float* wv3, const float* bv3,
    float* __restrict__ out)
{
    __shared__ float ssum[NC * DD];
    __shared__ int scnt[NC];
    __shared__ float hs[NC][DD];
    __shared__ float w_lds[DD * (DD + 1)];

    const int tid = threadIdx.x;
    const int b = blockIdx.x;
    const int wave = tid >> 6, lane = tid & 63;

    for (int i = tid; i < NC * DD; i += 1024) ssum[i] = 0.f;
    if (tid < NC) scnt[tid] = 0;
    __syncthreads();

    const int* lab = labels + b * SS;
    {
        int c_acc[NC];
        #pragma unroll
        for (int c = 0; c < NC; ++c) c_acc[c] = 0;
        for (int i = 0; i < 16; ++i) {
            int l = lab[wave * 1024 + i * 64 + lane];
            #pragma unroll
            for (int c = 0; c < NC; ++c)
                c_acc[c] += (int)__popcll(__ballot(l == c));
        }
        if (lane == 0) {
            #pragma unroll
            for (int c = 0; c < NC; ++c) atomicAdd(&scnt[c], c_acc[c]);
        }
    }

    const float* xb = x + ((long)b * SS + wave * 1024) * DD + lane;
    const int* labw = lab + wave * 1024;
    for (int r = 0; r < 1024; r += 8) {
        float v[8]; int l[8];
        #pragma unroll
        for (int u = 0; u < 8; ++u) { v[u] = xb[(r + u) * DD]; l[u] = labw[r + u]; }
        #pragma unroll
        for (int u = 0; u < 8; ++u) atomicAdd(&ssum[l[u] * DD + lane], v[u]);
    }
    __syncthreads();

    const int c = tid >> 6;
    const bool act = (tid < NC * DD);
    float slot = 0.f;
    if (act) slot = ssum[c * DD + lane] / (float)scnt[c];

    const float* Ws[2][3] = {{wm1, wm2, wm3}, {wv1, wv2, wv3}};
    const float* Bs[2][3] = {{bm1, bm2, bm3}, {bv1, bv2, bv3}};

    #pragma unroll
    for (int head = 0; head < 2; ++head) {
        if (act) hs[c][lane] = slot;
        float val = 0.f;
        #pragma unroll
        for (int layer = 0; layer < 3; ++layer) {
            const float* W = Ws[head][layer];
            for (int i = tid; i < DD * DD; i += 1024)
                w_lds[(i >> 6) * (DD + 1) + (i & 63)] = W[i];
            __syncthreads();
            if (act) {
                float z = Bs[head][layer][lane];
                #pragma unroll
                for (int d = 0; d < DD; ++d)
                    z += hs[c][d] * w_lds[lane * (DD + 1) + d];
                val = (layer < 2) ? fmaxf(z, 0.f)
                                  : (2.f / (1.f + __expf(-z)) - 1.f);
            }
            __syncthreads();
            if (act) hs[c][lane] = val;
        }
        if (act) out[head * (BB * NC * DD) + (b * NC + c) * DD + lane] = val;
        __syncthreads();
    }
}

__global__ __launch_bounds__(256) void init_fallback_kernel(
    const float* __restrict__ out_ro, const int* __restrict__ Kptr,
    float* __restrict__ out)
{
    const int head = blockIdx.x, tid = threadIdx.x;
    const int d = tid & 63, grp = tid >> 6;
    __shared__ float part[4][DD];

    const float* src = out_ro + head * (BB * NC * DD);
    float s = 0.f;
    for (int r0 = 0; r0 < 80; r0 += 8) {
        float t[8];
        #pragma unroll
        for (int u = 0; u < 8; ++u)
            t[u] = src[(grp + (r0 + u) * 4) * DD + d];
        #pragma unroll
        for (int u = 0; u < 8; ++u) s += t[u];
    }
    part[grp][d] = s;
    __syncthreads();
    if (tid < DD)
        out[OUT_MAIN + head * DD + tid] =
            (part[0][tid] + part[1][tid] + part[2][tid] + part[3][tid])
            / (float)(BB * Kptr[0]);
}

extern "C" void kernel_launch(void* const* d_in, const int* in_sizes, int n_in,
                              void* d_out, int out_size, void* d_ws, size_t ws_size,
                              hipStream_t stream)
{
    const float* x      = (const float*)d_in[0];
    const int*   labels = (const int*)d_in[1];
    const int*   K      = (const int*)d_in[2];
    const float* wm1 = (const float*)d_in[3];
    const float* bm1 = (const float*)d_in[4];
    const float* wm2 = (const float*)d_in[5];
    const float* bm2 = (const float*)d_in[6];
    const float* wm3 = (const float*)d_in[7];
    const float* bm3 = (const float*)d_in[8];
    const float* wv1 = (const float*)d_in[9];
    const float* bv1 = (const float*)d_in[10];
    const float* wv2 = (const float*)d_in[11];
    const float* bv2 = (const float*)d_in[12];
    const float* wv3 = (const float*)d_in[13];
    const float* bv3 = (const float*)d_in[14];
    float* out = (float*)d_out;

    if (ws_size >= (size_t)WS_WORDS * 4) {
        float* seg_part = (float*)d_ws;
        int*   cnt_part = (int*)((char*)d_ws + (size_t)SEG_WORDS * 4);
        seg_kernel<<<NBLK, 256, 0, stream>>>(x, labels, seg_part, cnt_part, out);
        mlp_kernel<<<2 * BB, 1024, 0, stream>>>(
            seg_part, cnt_part,
            wm1, bm1, wm2, bm2, wm3, bm3,
            wv1, bv1, wv2, bv2, wv3, bv3, K, out);
    } else {
        fused_fallback_kernel<<<BB, 1024, 0, stream>>>(
            x, labels,
            wm1, bm1, wm2, bm2, wm3, bm3,
            wv1, bv1, wv2, bv2, wv3, bv3, out);
        init_fallback_kernel<<<2, 256, 0, stream>>>((const float*)d_out, K, out);
    }
}